// Round 1
// baseline (490.712 us; speedup 1.0000x reference)
//
#include <hip/hip_runtime.h>
#include <hip/hip_bf16.h>

// Problem constants (from reference setup_inputs)
constexpr int B_DIM   = 64;
constexpr int S_DIM   = 2048;
constexpr int D_DIM   = 512;      // 128 float4 per row
constexpr int NMASK   = 1536;
constexpr int NUNMASK = 512;
constexpr float ALPHA = 0.1f;

constexpr int ROWS_PER_SAMPLE = NMASK + NUNMASK;          // 2048
constexpr int ROWS_TOTAL      = B_DIM * ROWS_PER_SAMPLE;  // 131072
constexpr int BLOCK           = 256;                      // 2 rows per block iter
constexpr int GRID            = 2048;                     // 32 row-iters per block

__global__ __launch_bounds__(BLOCK) void mae_loss_kernel(
    const float* __restrict__ outputs,
    const float* __restrict__ orig,
    const int*   __restrict__ mask_id,
    const int*   __restrict__ unmask_id,
    float*       __restrict__ out)
{
    const int lane_in_row  = threadIdx.x & 127;  // which float4 of the row
    const int row_in_block = threadIdx.x >> 7;   // 0 or 1

    const float wm = 1.0f / (float)((long long)B_DIM * NMASK   * D_DIM);
    const float wu = ALPHA / (float)((long long)B_DIM * NUNMASK * D_DIM);

    float acc = 0.0f;

    for (int r = blockIdx.x * 2 + row_in_block; r < ROWS_TOTAL; r += GRID * 2) {
        const int b = r >> 11;        // r / 2048
        const int j = r & 2047;       // r % 2048
        int   idx;
        float w;
        if (j < NMASK) {
            idx = mask_id[b * NMASK + j];
            w   = wm;
        } else {
            idx = unmask_id[b * NUNMASK + (j - NMASK)];
            w   = wu;
        }
        const size_t row_off = ((size_t)b * S_DIM + (size_t)idx) * D_DIM;
        const float4* po = (const float4*)(outputs + row_off);
        const float4* pt = (const float4*)(orig    + row_off);
        const float4 o = po[lane_in_row];
        const float4 t = pt[lane_in_row];
        const float dx = o.x - t.x;
        const float dy = o.y - t.y;
        const float dz = o.z - t.z;
        const float dw = o.w - t.w;
        acc += w * (dx * dx + dy * dy + dz * dz + dw * dw);
    }

    // wave (64-lane) shuffle reduction
    #pragma unroll
    for (int off = 32; off > 0; off >>= 1)
        acc += __shfl_down(acc, off, 64);

    __shared__ float sdata[BLOCK / 64];
    const int wid = threadIdx.x >> 6;
    if ((threadIdx.x & 63) == 0) sdata[wid] = acc;
    __syncthreads();

    if (threadIdx.x == 0) {
        float s = 0.0f;
        #pragma unroll
        for (int i = 0; i < BLOCK / 64; ++i) s += sdata[i];
        atomicAdd(out, s);
    }
}

extern "C" void kernel_launch(void* const* d_in, const int* in_sizes, int n_in,
                              void* d_out, int out_size, void* d_ws, size_t ws_size,
                              hipStream_t stream) {
    const float* outputs   = (const float*)d_in[0];
    const float* orig      = (const float*)d_in[1];
    const int*   mask_id   = (const int*)d_in[2];
    const int*   unmask_id = (const int*)d_in[3];
    float* out = (float*)d_out;

    // d_out is re-poisoned to 0xAA before every timed launch — zero it here.
    hipMemsetAsync(out, 0, sizeof(float), stream);

    mae_loss_kernel<<<GRID, BLOCK, 0, stream>>>(outputs, orig, mask_id, unmask_id, out);
}